// Round 1
// baseline (77.261 us; speedup 1.0000x reference)
//
#include <hip/hip_runtime.h>

#define IH 256
#define IW 256
#define NK 512
#define ZTH 3.0f
#define EPSV 1e-8f

__launch_bounds__(256, 4)
__global__ void slice_render_kernel(const float* __restrict__ positions,
                                    const float* __restrict__ scales,
                                    const float* __restrict__ opacity,
                                    const float* __restrict__ intensity,
                                    const float* __restrict__ z_target,
                                    float* __restrict__ out) {
    __shared__ float s_w[NK];
    __shared__ int   s_idx[NK];
    __shared__ float s_px[NK], s_py[NK], s_isx[NK], s_isy[NK], s_ew[NK], s_it[NK];
    __shared__ int   s_n;

    const int tid = threadIdx.x;
    const float zt = z_target[0];

    // 1) effective weights
    for (int k = tid; k < NK; k += 256) {
        float pz = positions[3 * k + 2];
        float sz = scales[3 * k + 2];
        float zd = (zt - pz) / (sz + EPSV);
        float w = 0.0f;
        if (fabsf(zd) < ZTH) w = opacity[k] * __expf(-0.5f * zd * zd);
        s_w[k]  = w;
        s_idx[k] = k;
    }

    // 2) bitonic sort: descending by w, ties ascending by original index
    //    (matches stable jnp.argsort(-eff_w))
    for (int size = 2; size <= NK; size <<= 1) {
        for (int stride = size >> 1; stride > 0; stride >>= 1) {
            __syncthreads();
            int p = tid;                       // NK/2 == 256 pairs == blockDim
            int i = ((p & ~(stride - 1)) << 1) | (p & (stride - 1));
            int j = i | stride;
            bool desc = ((i & size) == 0);
            float wi = s_w[i], wj = s_w[j];
            int   ii = s_idx[i], ij = s_idx[j];
            bool cb_ji = (wj > wi) || (wj == wi && ij < ii); // j belongs before i
            bool cb_ij = (wi > wj) || (wi == wj && ii < ij); // i belongs before j
            bool doswap = desc ? cb_ji : cb_ij;
            if (doswap) {
                s_w[i] = wj;  s_w[j] = wi;
                s_idx[i] = ij; s_idx[j] = ii;
            }
        }
    }
    __syncthreads();

    // 3) count of nonzero weights (sorted desc => first zero terminates)
    if (tid == 0) s_n = NK;
    __syncthreads();
    for (int k = tid; k < NK; k += 256) {
        if (s_w[k] == 0.0f && (k == 0 || s_w[k - 1] > 0.0f)) s_n = k;
    }
    __syncthreads();

    const int n = s_n;

    // 4) stage sorted gaussian params (only the active prefix)
    for (int k = tid; k < n; k += 256) {
        int j = s_idx[k];
        s_px[k]  = positions[3 * j + 0];
        s_py[k]  = positions[3 * j + 1];
        s_isx[k] = 1.0f / (scales[3 * j + 0] + EPSV);
        s_isy[k] = 1.0f / (scales[3 * j + 1] + EPSV);
        s_ew[k]  = s_w[k];
        s_it[k]  = intensity[j];
    }
    __syncthreads();

    // 5) per-pixel front-to-back compositing; block = one image row
    const float y = (float)blockIdx.x;
    const float x = (float)tid;
    float T = 1.0f;
    float acc = 0.0f;
    for (int k = 0; k < n; ++k) {
        float dx = (y - s_px[k]) * s_isx[k];
        float dy = (x - s_py[k]) * s_isy[k];
        float g  = __expf(-0.5f * (dx * dx + dy * dy));
        float a  = fminf(g * s_ew[k], 0.99f);
        acc += T * a * s_it[k];
        T   *= 1.0f - a;
        if (__all(T < 1e-6f)) break;   // remaining contribution <= T <= 1e-6
    }
    out[blockIdx.x * IW + tid] = acc;
}

extern "C" void kernel_launch(void* const* d_in, const int* in_sizes, int n_in,
                              void* d_out, int out_size, void* d_ws, size_t ws_size,
                              hipStream_t stream) {
    (void)in_sizes; (void)n_in; (void)out_size; (void)d_ws; (void)ws_size;
    const float* positions = (const float*)d_in[0];
    const float* scales    = (const float*)d_in[1];
    const float* opacity   = (const float*)d_in[2];
    const float* intensity = (const float*)d_in[3];
    const float* z_target  = (const float*)d_in[4];
    float* out = (float*)d_out;
    hipLaunchKernelGGL(slice_render_kernel, dim3(IH), dim3(256), 0, stream,
                       positions, scales, opacity, intensity, z_target, out);
}

// Round 2
// 74.539 us; speedup vs baseline: 1.0365x; 1.0365x over previous
//
#include <hip/hip_runtime.h>

#define IH 256
#define IW 256
#define NK 512
#define ZTH 3.0f
#define EPSV 1e-8f

// ws layout (floats): [0]=n (as int bits), arrays at 64-float-aligned offsets
#define WS_PX  64
#define WS_PY  (WS_PX + NK)
#define WS_ISY (WS_PY + NK)
#define WS_ISX (WS_ISY + NK)
#define WS_EW  (WS_ISX + NK)
#define WS_IT  (WS_EW + NK)

// ---------------- kernel A: weights -> compact -> sort -> stage to ws ----------------
__launch_bounds__(256, 4)
__global__ void prep_kernel(const float* __restrict__ positions,
                            const float* __restrict__ scales,
                            const float* __restrict__ opacity,
                            const float* __restrict__ intensity,
                            const float* __restrict__ z_target,
                            float* __restrict__ ws) {
    __shared__ float s_w[NK];
    __shared__ int   s_idx[NK];
    __shared__ int   s_cnt;

    const int tid = threadIdx.x;
    const float zt = z_target[0];

    if (tid == 0) s_cnt = 0;
    __syncthreads();

    // compute z-weight; compact active gaussians (order fixed later by full sort)
    for (int k = tid; k < NK; k += 256) {
        float pz = positions[3 * k + 2];
        float sz = scales[3 * k + 2];
        float zd = (zt - pz) / (sz + EPSV);
        float w = 0.0f;
        if (fabsf(zd) < ZTH) w = opacity[k] * __expf(-0.5f * zd * zd);
        if (w > 0.0f) {
            int p = atomicAdd(&s_cnt, 1);
            s_w[p] = w;
            s_idx[p] = k;
        }
    }
    __syncthreads();

    const int m = s_cnt;
    int msort = 2;
    while (msort < m) msort <<= 1;

    // pad to pow2 with sentinels that sort last
    for (int k = m + tid; k < msort; k += 256) { s_w[k] = -1.0f; s_idx[k] = NK; }

    // bitonic sort: descending by w, ties ascending by original index
    // (matches stable jnp.argsort(-eff_w); zero-weight entries were dropped
    //  above — they contribute exactly 0 regardless of position)
    const int half = msort >> 1;
    for (int size = 2; size <= msort; size <<= 1) {
        for (int stride = size >> 1; stride > 0; stride >>= 1) {
            __syncthreads();
            for (int p = tid; p < half; p += 256) {
                int i = ((p & ~(stride - 1)) << 1) | (p & (stride - 1));
                int j = i | stride;
                bool desc = ((i & size) == 0);
                float wi = s_w[i], wj = s_w[j];
                int   ii = s_idx[i], ij = s_idx[j];
                bool cb_ji = (wj > wi) || (wj == wi && ij < ii);
                bool cb_ij = (wi > wj) || (wi == wj && ii < ij);
                if (desc ? cb_ji : cb_ij) {
                    s_w[i] = wj;  s_w[j] = wi;
                    s_idx[i] = ij; s_idx[j] = ii;
                }
            }
        }
    }
    __syncthreads();

    if (tid == 0) ((int*)ws)[0] = m;
    for (int k = tid; k < m; k += 256) {
        int j = s_idx[k];
        ws[WS_PX  + k] = positions[3 * j + 0];
        ws[WS_PY  + k] = positions[3 * j + 1];
        ws[WS_ISX + k] = 1.0f / (scales[3 * j + 0] + EPSV);
        ws[WS_ISY + k] = 1.0f / (scales[3 * j + 1] + EPSV);
        ws[WS_EW  + k] = s_w[k];
        ws[WS_IT  + k] = intensity[j];
    }
}

// ---------------- kernel B: per-row composite (block = image row) ----------------
__launch_bounds__(256, 4)
__global__ void render_kernel(const float* __restrict__ ws,
                              float* __restrict__ out) {
    __shared__ int   s_n;
    __shared__ float s_py[NK], s_isy[NK], s_rowfac[NK], s_it[NK];

    const int tid = threadIdx.x;
    if (tid == 0) s_n = ((const int*)ws)[0];
    __syncthreads();
    const int n = s_n;

    const float y = (float)blockIdx.x;

    // stage + fold the row-dependent gaussian factor:
    // gauss = exp(-0.5*dxn^2) * exp(-0.5*dyn^2); dxn depends only on the row.
    for (int k = tid; k < n; k += 256) {
        float px  = ws[WS_PX + k];
        float isx = ws[WS_ISX + k];
        float dx  = (y - px) * isx;
        s_rowfac[k] = __expf(-0.5f * dx * dx) * ws[WS_EW + k];
        s_py[k]   = ws[WS_PY + k];
        s_isy[k]  = ws[WS_ISY + k];
        s_it[k]   = ws[WS_IT + k];
    }
    __syncthreads();

    const float x = (float)tid;
    float T = 1.0f;
    float acc = 0.0f;
    for (int k = 0; k < n; ++k) {
        float dy = (x - s_py[k]) * s_isy[k];
        float a  = fminf(__expf(-0.5f * dy * dy) * s_rowfac[k], 0.99f);
        acc += T * a * s_it[k];
        T   *= 1.0f - a;
        if (__all(T < 1e-6f)) break;   // residual contribution <= 1e-6
    }
    out[blockIdx.x * IW + tid] = acc;
}

extern "C" void kernel_launch(void* const* d_in, const int* in_sizes, int n_in,
                              void* d_out, int out_size, void* d_ws, size_t ws_size,
                              hipStream_t stream) {
    (void)in_sizes; (void)n_in; (void)out_size; (void)ws_size;
    const float* positions = (const float*)d_in[0];
    const float* scales    = (const float*)d_in[1];
    const float* opacity   = (const float*)d_in[2];
    const float* intensity = (const float*)d_in[3];
    const float* z_target  = (const float*)d_in[4];
    float* out = (float*)d_out;
    float* ws  = (float*)d_ws;

    hipLaunchKernelGGL(prep_kernel, dim3(1), dim3(256), 0, stream,
                       positions, scales, opacity, intensity, z_target, ws);
    hipLaunchKernelGGL(render_kernel, dim3(IH), dim3(256), 0, stream,
                       ws, out);
}